// Round 5
// baseline (1814.677 us; speedup 1.0000x reference)
//
#include <hip/hip_runtime.h>
#include <hip/hip_bf16.h>

#define T_LEN 1024
#define NT 128   // tagset size
#define SEQ 4    // sequences (batches) per block
#define CHUNK 8  // feats rows staged per chunk per seq
#define NCHUNK (T_LEN / CHUNK)

// Raw barrier: drain LDS ops (write visibility) but NOT vmcnt, so staged
// global_load_lds chunks stay in flight across per-step barriers.
__device__ __forceinline__ void bar_lds() {
  asm volatile("s_waitcnt lgkmcnt(0)" ::: "memory");
  __builtin_amdgcn_s_barrier();
}

__device__ __forceinline__ unsigned short f2bf(float x) {
  __hip_bfloat16 h = __float2bfloat16(x);  // RNE
  return *reinterpret_cast<unsigned short*>(&h);
}
__device__ __forceinline__ float bf_lo(unsigned int d) {
  return __uint_as_float(d << 16);
}
__device__ __forceinline__ float bf_hi(unsigned int d) {
  return __uint_as_float(d & 0xffff0000u);
}

__device__ __forceinline__ void gload16(const float* g, float* l) {
  __builtin_amdgcn_global_load_lds(
      (const __attribute__((address_space(1))) unsigned int*)g,
      (__attribute__((address_space(3))) unsigned int*)l, 16, 0, 0);
}

// One block = SEQ batches, 4 waves (256 thr). Lane layout:
//   l15 = lane&15, q = lane>>4 (i-quarter of 32), outputs j0=16w+l15, j0+64.
// E (exp(trans) fragment, 64 VGPR) is SHARED across the SEQ sequences.
// Per step x seq: 4x ds_read_b128 of bf16 u, 64 fmacs, 4x shfl_xor, one bf16
// write. ONE lgkm-only barrier per step for all SEQ seqs. Lag normalization
// by previous u[0]: u'_j = (sum_i E[j][i] u_i)*rcp(u[0])*exp(f_t[j]-f_t[0]),
// C_s += log(u[0]) + f_t[0]. Feats staged global->LDS per seq in 8-step
// chunks, double buffered, counted vmcnt once per chunk.
__global__ __launch_bounds__(256, 1) void crf_forward_kernel(
    const float* __restrict__ feats, const float* __restrict__ trans,
    const float* __restrict__ start, const float* __restrict__ stop,
    float* __restrict__ fwd_out) {
  const int b0 = blockIdx.x * SEQ;
  const int tid = (int)threadIdx.x;
  const int lane = tid & 63;
  const int w = tid >> 6;       // wave 0..3
  const int l15 = lane & 15;
  const int q = lane >> 4;      // i-quarter 0..3
  const int j0 = 16 * w + l15;  // low output tag
  const int jw = j0 + ((lane & 16) ? 64 : 0);  // this lane's write/f index

  alignas(16) __shared__ unsigned short pbuf[SEQ][2][NT];    // u, bf16, dbuf
  alignas(16) __shared__ float fstage[SEQ][2][CHUNK * NT];   // feats stage
  __shared__ float wred_unused[4];
  (void)wred_unused;

  const float* fb[SEQ];
#pragma unroll
  for (int s = 0; s < SEQ; ++s) fb[s] = feats + (size_t)(b0 + s) * T_LEN * NT;

  // ---- stage: one dwordx4 per thread per (seq, chunk): 8 rows = 4KB
#define STAGE(s, c, buf) \
  gload16(fb[s] + (c) * (CHUNK * NT) + tid * 4, &fstage[s][buf][tid * 4]);

#pragma unroll
  for (int s = 0; s < SEQ; ++s) STAGE(s, 0, 0)
#pragma unroll
  for (int s = 0; s < SEQ; ++s) STAGE(s, 1, 1)

  // E0[i] = exp(trans[j0][32q+i]), E1[i] = exp(trans[j0+64][32q+i]), i=0..31
  float E0[32], E1[32];
#pragma unroll
  for (int n = 0; n < 8; ++n) {
    float4 t0 =
        *reinterpret_cast<const float4*>(&trans[j0 * NT + 32 * q + 4 * n]);
    float4 t1 = *reinterpret_cast<const float4*>(
        &trans[(j0 + 64) * NT + 32 * q + 4 * n]);
    E0[4 * n + 0] = __expf(t0.x); E0[4 * n + 1] = __expf(t0.y);
    E0[4 * n + 2] = __expf(t0.z); E0[4 * n + 3] = __expf(t0.w);
    E1[4 * n + 0] = __expf(t1.x); E1[4 * n + 1] = __expf(t1.y);
    E1[4 * n + 2] = __expf(t1.z); E1[4 * n + 3] = __expf(t1.w);
  }

  // init: u_0[j] = exp(start[j]+f_0[j] - base_s), C_s = base_s
  float C[SEQ];
#pragma unroll
  for (int s = 0; s < SEQ; ++s) {
    float base = start[0] + fb[s][0];
    if (tid < NT) pbuf[s][0][tid] = f2bf(__expf(start[tid] + fb[s][tid] - base));
    C[s] = base;
  }

  int cur = 0;

  // ---- one step for seq s at row trow of chunk-parity fc ----
#define STEP(s, fc, trow)                                                  \
  {                                                                        \
    const unsigned short* pb = &pbuf[s][cur][q * 32];                      \
    float u0 = bf_lo((unsigned int)pbuf[s][cur][0]);                       \
    float f_me = fstage[s][fc][(trow) * NT + jw];                          \
    float f_0 = fstage[s][fc][(trow) * NT];                                \
    float a00 = 0.f, a01 = 0.f, a10 = 0.f, a11 = 0.f;                      \
    _Pragma("unroll") for (int n = 0; n < 4; ++n) {                        \
      uint4 d4 = *reinterpret_cast<const uint4*>(pb + 8 * n);              \
      {                                                                    \
        float lo = bf_lo(d4.x), hi = bf_hi(d4.x);                          \
        a00 = fmaf(lo, E0[8 * n + 0], a00);                                \
        a01 = fmaf(hi, E0[8 * n + 1], a01);                                \
        a10 = fmaf(lo, E1[8 * n + 0], a10);                                \
        a11 = fmaf(hi, E1[8 * n + 1], a11);                                \
      }                                                                    \
      {                                                                    \
        float lo = bf_lo(d4.y), hi = bf_hi(d4.y);                          \
        a00 = fmaf(lo, E0[8 * n + 2], a00);                                \
        a01 = fmaf(hi, E0[8 * n + 3], a01);                                \
        a10 = fmaf(lo, E1[8 * n + 2], a10);                                \
        a11 = fmaf(hi, E1[8 * n + 3], a11);                                \
      }                                                                    \
      {                                                                    \
        float lo = bf_lo(d4.z), hi = bf_hi(d4.z);                          \
        a00 = fmaf(lo, E0[8 * n + 4], a00);                                \
        a01 = fmaf(hi, E0[8 * n + 5], a01);                                \
        a10 = fmaf(lo, E1[8 * n + 4], a10);                                \
        a11 = fmaf(hi, E1[8 * n + 5], a11);                                \
      }                                                                    \
      {                                                                    \
        float lo = bf_lo(d4.w), hi = bf_hi(d4.w);                          \
        a00 = fmaf(lo, E0[8 * n + 6], a00);                                \
        a01 = fmaf(hi, E0[8 * n + 7], a01);                                \
        a10 = fmaf(lo, E1[8 * n + 6], a10);                                \
        a11 = fmaf(hi, E1[8 * n + 7], a11);                                \
      }                                                                    \
    }                                                                      \
    float eterm = __expf(f_me - f_0);                                      \
    float re = __builtin_amdgcn_rcpf(u0) * eterm;                          \
    float s0 = a00 + a01;                                                  \
    s0 += __shfl_xor(s0, 16);                                              \
    s0 += __shfl_xor(s0, 32);                                              \
    float s1 = a10 + a11;                                                  \
    s1 += __shfl_xor(s1, 16);                                              \
    s1 += __shfl_xor(s1, 32);                                              \
    float sv = (lane & 16) ? s1 : s0;                                      \
    float unew = sv * re;                                                  \
    if (lane < 32) pbuf[s][cur ^ 1][jw] = f2bf(unew);                      \
    C[s] += __logf(u0) + f_0;                                              \
  }

  // wait chunk 0 of all seqs (8 loads in flight; oldest 4 = chunk 0 set),
  // and make pbuf init visible.
  asm volatile("s_waitcnt vmcnt(4)" ::: "memory");
  bar_lds();

  // chunk 0: rows 1..7 (row 0 is t=0, consumed by init)
  for (int trow = 1; trow < CHUNK; ++trow) {
    STEP(0, 0, trow) STEP(1, 0, trow) STEP(2, 0, trow) STEP(3, 0, trow)
    bar_lds();
    cur ^= 1;
  }

  // chunks 1..NCHUNK-1
  for (int c = 1; c < NCHUNK; ++c) {
    if (c + 1 < NCHUNK) {
#pragma unroll
      for (int s = 0; s < SEQ; ++s) STAGE(s, c + 1, (c + 1) & 1)
      asm volatile("s_waitcnt vmcnt(4)" ::: "memory");
    } else {
      asm volatile("s_waitcnt vmcnt(0)" ::: "memory");
    }
    __builtin_amdgcn_s_barrier();  // chunk c visible to all waves
    const int fc = c & 1;
    for (int trow = 0; trow < CHUNK; ++trow) {
      STEP(0, fc, trow) STEP(1, fc, trow) STEP(2, fc, trow) STEP(3, fc, trow)
      bar_lds();
      cur ^= 1;
    }
  }
#undef STEP
#undef STAGE

  // final: wave w reduces seq w: ans = C_w + log(sum_j u[j]*exp(stop[j]))
  {
    float v0 = bf_lo((unsigned int)pbuf[w][cur][lane]) * __expf(stop[lane]);
    float v1 =
        bf_lo((unsigned int)pbuf[w][cur][lane + 64]) * __expf(stop[lane + 64]);
    float val = v0 + v1;
#pragma unroll
    for (int off = 1; off <= 32; off <<= 1) val += __shfl_xor(val, off);
    if (lane == 0) fwd_out[b0 + w] = C[w] + __logf(val);
  }
}

__global__ __launch_bounds__(256) void crf_gold_kernel(
    const float* __restrict__ feats, const float* __restrict__ trans,
    const float* __restrict__ start, const float* __restrict__ stop,
    const int* __restrict__ tags, const float* __restrict__ fwd,
    float* __restrict__ diff) {
  const int b = blockIdx.x;
  const int tid = (int)threadIdx.x;
  const int lane = tid & 63;
  const int w = tid >> 6;
  const int* tg = tags + b * T_LEN;
  const float* fb = feats + (size_t)b * T_LEN * NT;

  float acc = 0.f;
  for (int s = tid; s < T_LEN; s += 256) {
    int cu = tg[s];
    acc += fb[s * NT + cu];
    if (s > 0) acc += trans[cu * NT + tg[s - 1]];
  }
#pragma unroll
  for (int off = 1; off <= 32; off <<= 1) acc += __shfl_xor(acc, off);
  __shared__ float wr[4];
  if (lane == 0) wr[w] = acc;
  __syncthreads();
  if (tid == 0) {
    float gold = (wr[0] + wr[1]) + (wr[2] + wr[3]) + start[tg[0]] +
                 stop[tg[T_LEN - 1]];
    diff[b] = fwd[b] - gold;
  }
}

__global__ __launch_bounds__(128) void crf_final_kernel(
    const float* __restrict__ diff, float* __restrict__ out) {
  const int tid = (int)threadIdx.x;
  const int lane = tid & 63;
  const int w = tid >> 6;
  float v = diff[tid];
#pragma unroll
  for (int off = 1; off <= 32; off <<= 1) v += __shfl_xor(v, off);
  __shared__ float wr[2];
  if (lane == 0) wr[w] = v;
  __syncthreads();
  if (tid == 0) out[0] = (wr[0] + wr[1]) * (1.0f / 128.0f);
}

extern "C" void kernel_launch(void* const* d_in, const int* in_sizes, int n_in,
                              void* d_out, int out_size, void* d_ws,
                              size_t ws_size, hipStream_t stream) {
  const float* feats = (const float*)d_in[0];
  const float* trans = (const float*)d_in[1];
  const float* start = (const float*)d_in[2];
  const float* stop = (const float*)d_in[3];
  const int* tags = (const int*)d_in[4];
  // d_in[5] = mask: all-true for this problem; ignored.
  float* ws = (float*)d_ws;
  float* fwd = ws;         // 128 floats
  float* diff = ws + 128;  // 128 floats
  float* out = (float*)d_out;

  crf_forward_kernel<<<128 / SEQ, 256, 0, stream>>>(feats, trans, start, stop,
                                                    fwd);
  crf_gold_kernel<<<128, 256, 0, stream>>>(feats, trans, start, stop, tags, fwd,
                                           diff);
  crf_final_kernel<<<1, 128, 0, stream>>>(diff, out);
}

// Round 6
// 665.034 us; speedup vs baseline: 2.7287x; 2.7287x over previous
//
#include <hip/hip_runtime.h>
#include <hip/hip_bf16.h>

#define T_LEN 1024
#define NT 128    // tagset size
#define CHUNK 16  // feats rows staged per chunk
#define NCHUNK (T_LEN / CHUNK)
#define LOG128 4.852030263919617f

typedef _Float16 h2 __attribute__((ext_vector_type(2)));

#if defined(__has_builtin)
#if __has_builtin(__builtin_amdgcn_fdot2)
#define HAVE_FDOT2 1
#endif
#endif

__device__ __forceinline__ float dot2(h2 a, h2 b, float c) {
#ifdef HAVE_FDOT2
  return __builtin_amdgcn_fdot2(a, b, c, false);
#else
  return fmaf((float)a.x, (float)b.x, fmaf((float)a.y, (float)b.y, c));
#endif
}

__device__ __forceinline__ h2 u2h(unsigned int u) {
  return __builtin_bit_cast(h2, u);
}

// Raw barrier: drain LDS ops but NOT vmcnt, so staged global_load_lds
// chunks stay in flight across per-step barriers.
__device__ __forceinline__ void bar_lds() {
  asm volatile("s_waitcnt lgkmcnt(0)" ::: "memory");
  __builtin_amdgcn_s_barrier();
}

__device__ __forceinline__ void gload16(const float* g, float* l) {
  __builtin_amdgcn_global_load_lds(
      (const __attribute__((address_space(1))) unsigned int*)g,
      (__attribute__((address_space(3))) unsigned int*)l, 16, 0, 0);
}

// One block per batch, 2 waves (128 thr). Lane layout: thread tid owns
// output tag j = tid (0..127). Each step: 16 broadcast ds_read_b128 pull the
// full f16 u[128]; 64 v_dot2_f32_f16 against the register-resident f16
// E row exp(trans[j][:]); scale by rcp(u0)*exp(f_t[j]-f_t[0])/128; one
// ds_write_b16; ONE lgkm-only barrier. NO cross-lane ops.
// Invariant: fv_t[j] = log(u_t[j]) + C_t,
//   C_t = C_{t-1} + f_t[0] + log(u_{t-1}[0]) + log(128).
// Feats staged global->LDS in 16-row chunks, double buffered, counted vmcnt.
__global__ __launch_bounds__(128, 1) void crf_forward_kernel(
    const float* __restrict__ feats, const float* __restrict__ trans,
    const float* __restrict__ start, const float* __restrict__ stop,
    float* __restrict__ fwd_out) {
  const int b = blockIdx.x;
  const int tid = (int)threadIdx.x;  // == output tag j
  const int lane = tid & 63;
  const int w = tid >> 6;  // wave 0..1

  alignas(16) __shared__ unsigned short pbuf[2][NT];   // u, f16, dbuf
  alignas(16) __shared__ float fstage[2][CHUNK * NT];  // 2 x 8 KB feats
  __shared__ float wred[2];

  const float* fb = feats + (size_t)b * T_LEN * NT;

  // ---- stage chunk c into buffer buf: 4 dwordx4 per thread
#define STAGE(c, buf)                                                 \
  {                                                                   \
    _Pragma("unroll") for (int seg = 0; seg < 4; ++seg) {             \
      const float* g = fb + (c) * (CHUNK * NT) + seg * 512 + tid * 4; \
      float* l = &fstage[buf][seg * 512 + w * 256 + lane * 4];        \
      gload16(g, l);                                                  \
    }                                                                 \
  }
  STAGE(0, 0)
  STAGE(1, 1)

  // E[m] = (exp(trans[j][2m]), exp(trans[j][2m+1])), m = 0..63, f16 packed.
  h2 E[64];
#pragma unroll
  for (int n = 0; n < 32; ++n) {
    float4 t4 = *reinterpret_cast<const float4*>(&trans[tid * NT + 4 * n]);
    h2 e0; e0.x = (_Float16)__expf(t4.x); e0.y = (_Float16)__expf(t4.y);
    h2 e1; e1.x = (_Float16)__expf(t4.z); e1.y = (_Float16)__expf(t4.w);
    E[2 * n] = e0;
    E[2 * n + 1] = e1;
  }

  // init: u_0[j] = exp(start[j]+f_0[j] - base), C = base = start[0]+f_0[0]
  float base = start[0] + fb[0];
  {
    _Float16 h = (_Float16)__expf(start[tid] + fb[tid] - base);
    pbuf[0][tid] = __builtin_bit_cast(unsigned short, h);
  }
  float C = base;

  int cur = 0;

  // ---- one step at row trow of chunk-parity fc ----
#define STEP(fc, trow)                                                     \
  {                                                                        \
    const uint4* pb = reinterpret_cast<const uint4*>(&pbuf[cur][0]);       \
    float f_me = fstage[fc][(trow) * NT + tid];                            \
    float f_0 = fstage[fc][(trow) * NT];                                   \
    float a0 = 0.f, a1 = 0.f, a2 = 0.f, a3 = 0.f;                          \
    float u0 = 0.f;                                                        \
    _Pragma("unroll") for (int m = 0; m < 16; ++m) {                       \
      uint4 d = pb[m];                                                     \
      if (m == 0) u0 = (float)u2h(d.x).x;                                  \
      a0 = dot2(u2h(d.x), E[4 * m + 0], a0);                               \
      a1 = dot2(u2h(d.y), E[4 * m + 1], a1);                               \
      a2 = dot2(u2h(d.z), E[4 * m + 2], a2);                               \
      a3 = dot2(u2h(d.w), E[4 * m + 3], a3);                               \
    }                                                                      \
    float eterm = __expf(f_me - f_0);                                      \
    float scale = __builtin_amdgcn_rcpf(u0) * eterm * 0.0078125f;          \
    float unew = ((a0 + a1) + (a2 + a3)) * scale;                          \
    _Float16 hn = (_Float16)unew;                                          \
    pbuf[cur ^ 1][tid] = __builtin_bit_cast(unsigned short, hn);           \
    C += __logf(u0) + f_0 + LOG128;                                        \
    bar_lds();                                                             \
    cur ^= 1;                                                              \
  }

  // wait chunk 0 (8 loads in flight; oldest 4 are chunk 0), sync pbuf init
  asm volatile("s_waitcnt vmcnt(4)" ::: "memory");
  bar_lds();

  // chunk 0: rows 1..CHUNK-1 (row 0 is t=0, consumed by init)
  for (int trow = 1; trow < CHUNK; ++trow) STEP(0, trow)

  // chunks 1..NCHUNK-1
  for (int c = 1; c < NCHUNK; ++c) {
    if (c + 1 < NCHUNK) {
      STAGE(c + 1, (c + 1) & 1)
      asm volatile("s_waitcnt vmcnt(4)" ::: "memory");
    } else {
      asm volatile("s_waitcnt vmcnt(0)" ::: "memory");
    }
    __builtin_amdgcn_s_barrier();  // chunk c visible to both waves
    const int fc = c & 1;
    for (int trow = 0; trow < CHUNK; ++trow) STEP(fc, trow)
  }
#undef STEP
#undef STAGE

  // final: ans = C + log( sum_j u[j]*exp(stop[j]) ); final u is in pbuf[cur]
  {
    _Float16 hu =
        __builtin_bit_cast(_Float16, (unsigned short)pbuf[cur][tid]);
    float val = (float)hu * __expf(stop[tid]);
#pragma unroll
    for (int off = 1; off <= 32; off <<= 1) val += __shfl_xor(val, off);
    if (lane == 0) wred[w] = val;
    bar_lds();
    if (tid == 0) fwd_out[b] = C + __logf(wred[0] + wred[1]);
  }
}

__global__ __launch_bounds__(256) void crf_gold_kernel(
    const float* __restrict__ feats, const float* __restrict__ trans,
    const float* __restrict__ start, const float* __restrict__ stop,
    const int* __restrict__ tags, const float* __restrict__ fwd,
    float* __restrict__ diff) {
  const int b = blockIdx.x;
  const int tid = (int)threadIdx.x;
  const int lane = tid & 63;
  const int w = tid >> 6;
  const int* tg = tags + b * T_LEN;
  const float* fb = feats + (size_t)b * T_LEN * NT;

  float acc = 0.f;
  for (int s = tid; s < T_LEN; s += 256) {
    int cu = tg[s];
    acc += fb[s * NT + cu];
    if (s > 0) acc += trans[cu * NT + tg[s - 1]];
  }
#pragma unroll
  for (int off = 1; off <= 32; off <<= 1) acc += __shfl_xor(acc, off);
  __shared__ float wr[4];
  if (lane == 0) wr[w] = acc;
  __syncthreads();
  if (tid == 0) {
    float gold = (wr[0] + wr[1]) + (wr[2] + wr[3]) + start[tg[0]] +
                 stop[tg[T_LEN - 1]];
    diff[b] = fwd[b] - gold;
  }
}

__global__ __launch_bounds__(128) void crf_final_kernel(
    const float* __restrict__ diff, float* __restrict__ out) {
  const int tid = (int)threadIdx.x;
  const int lane = tid & 63;
  const int w = tid >> 6;
  float v = diff[tid];
#pragma unroll
  for (int off = 1; off <= 32; off <<= 1) v += __shfl_xor(v, off);
  __shared__ float wr[2];
  if (lane == 0) wr[w] = v;
  __syncthreads();
  if (tid == 0) out[0] = (wr[0] + wr[1]) * (1.0f / 128.0f);
}

extern "C" void kernel_launch(void* const* d_in, const int* in_sizes, int n_in,
                              void* d_out, int out_size, void* d_ws,
                              size_t ws_size, hipStream_t stream) {
  const float* feats = (const float*)d_in[0];
  const float* trans = (const float*)d_in[1];
  const float* start = (const float*)d_in[2];
  const float* stop = (const float*)d_in[3];
  const int* tags = (const int*)d_in[4];
  // d_in[5] = mask: all-true for this problem; ignored.
  float* ws = (float*)d_ws;
  float* fwd = ws;         // 128 floats
  float* diff = ws + 128;  // 128 floats
  float* out = (float*)d_out;

  crf_forward_kernel<<<128, 128, 0, stream>>>(feats, trans, start, stop, fwd);
  crf_gold_kernel<<<128, 256, 0, stream>>>(feats, trans, start, stop, tags, fwd,
                                           diff);
  crf_final_kernel<<<1, 128, 0, stream>>>(diff, out);
}

// Round 7
// 527.070 us; speedup vs baseline: 3.4430x; 1.2618x over previous
//
#include <hip/hip_runtime.h>
#include <hip/hip_bf16.h>

#define T_LEN 1024
#define NT 128    // tagset size
#define CHUNK 16  // feats rows per staged chunk
#define NCHUNK (T_LEN / CHUNK)

typedef short bf16x8 __attribute__((ext_vector_type(8)));
typedef float f32x4 __attribute__((ext_vector_type(4)));

__device__ __forceinline__ void gload16(const float* g, float* l) {
  __builtin_amdgcn_global_load_lds(
      (const __attribute__((address_space(1))) unsigned int*)g,
      (__attribute__((address_space(3))) unsigned int*)l, 16, 0, 0);
}

__device__ __forceinline__ short f2bf(float x) {
  __hip_bfloat16 h = __float2bfloat16(x);  // RNE
  return *reinterpret_cast<short*>(&h);
}

// ONE WAVE per sequence. The 128x128 matvec u' = E*u is done purely in
// registers with mfma_f32_16x16x32_bf16 (8 m-tiles x 4 k-tiles = 32 mfma).
// Index mapping chosen so C-fragment ownership == next B-fragment needs:
//   global row of (mt, tile-row m): P = 32*(m>>2) + 4*mt + (m&3)
//   global col of (kt, slot(g,e)):  32*g + 8*kt + e      (g = lane>>4)
// C layout (verified): lane holds rows m=4g+r, col=lane&15 (replicated) ->
// lane owns globals {32g+4mt+r} == {32g+0..31} == exactly what B needs.
// So step chaining = register renaming. No LDS/barrier/shuffle on the chain.
// Normalizer u0 = raw (E*u)[0] via v_readlane; C += log(u0).
// u''[j] = (E*u)[j] * rcp(u0) * exp(f_t[j]). feats exp-precomputed per chunk.
__global__ __launch_bounds__(64, 1) void crf_forward_kernel(
    const float* __restrict__ feats, const float* __restrict__ trans,
    const float* __restrict__ start, const float* __restrict__ stop,
    float* __restrict__ fwd_out) {
  const int b = blockIdx.x;
  const int tid = (int)threadIdx.x;  // 0..63
  const int c = tid & 15;            // A-row lane index / B col
  const int g = tid >> 4;            // k-slot group

  __shared__ float fraw[2][CHUNK * NT];  // raw feats chunks (2 x 8 KB)
  __shared__ float fexp[CHUNK * NT];     // exp(feats) for current chunk (8 KB)

  const float* fb = feats + (size_t)b * T_LEN * NT;

  // ---- E fragments: E[mt][kt], lane elem e = exp(trans[P(mt,c)][32g+8kt+e])
  bf16x8 E[8][4];
  const int rbase = 32 * (c >> 2) + (c & 3);
#pragma unroll
  for (int mt = 0; mt < 8; ++mt) {
    const float* tr = trans + (size_t)(rbase + 4 * mt) * NT + 32 * g;
#pragma unroll
    for (int kt = 0; kt < 4; ++kt) {
      float4 e0 = *reinterpret_cast<const float4*>(tr + 8 * kt);
      float4 e1 = *reinterpret_cast<const float4*>(tr + 8 * kt + 4);
      bf16x8 f;
      f[0] = f2bf(__expf(e0.x)); f[1] = f2bf(__expf(e0.y));
      f[2] = f2bf(__expf(e0.z)); f[3] = f2bf(__expf(e0.w));
      f[4] = f2bf(__expf(e1.x)); f[5] = f2bf(__expf(e1.y));
      f[6] = f2bf(__expf(e1.z)); f[7] = f2bf(__expf(e1.w));
      E[mt][kt] = f;
    }
  }

  // start[32g + idx] for init, and start[0]
  float sv[32];
#pragma unroll
  for (int m = 0; m < 8; ++m) {
    float4 s4 = *reinterpret_cast<const float4*>(start + 32 * g + 4 * m);
    sv[4 * m + 0] = s4.x; sv[4 * m + 1] = s4.y;
    sv[4 * m + 2] = s4.z; sv[4 * m + 3] = s4.w;
  }
  float st0 = start[0];

  // ---- stage chunk ch into fraw[buf]: 8 x global_load_lds_dwordx4
#define STAGE(ch, buf)                                                     \
  {                                                                        \
    _Pragma("unroll") for (int seg = 0; seg < 8; ++seg)                    \
        gload16(fb + (ch) * (CHUNK * NT) + seg * 256 + tid * 4,            \
                &fraw[buf][seg * 256 + tid * 4]);                          \
  }
  // ---- exp-pass: fexp = exp(fraw[buf])
#define EXPPASS(buf)                                                       \
  {                                                                        \
    _Pragma("unroll") for (int m8 = 0; m8 < 8; ++m8) {                     \
      float4 v =                                                           \
          *reinterpret_cast<const float4*>(&fraw[buf][m8 * 256 + tid * 4]);\
      float4 o;                                                            \
      o.x = __expf(v.x); o.y = __expf(v.y);                                \
      o.z = __expf(v.z); o.w = __expf(v.w);                                \
      *reinterpret_cast<float4*>(&fexp[m8 * 256 + tid * 4]) = o;           \
    }                                                                      \
  }

  STAGE(0, 0)
  STAGE(1, 1)
  asm volatile("s_waitcnt vmcnt(8)" ::: "memory");  // chunk 0 landed
  EXPPASS(0)

  // ---- init: u''_0[idx] = exp(start[32g+idx] + f_0[32g+idx] - C0)
  float Cacc = st0 + fraw[0][0];
  float uf[32];
#pragma unroll
  for (int m = 0; m < 8; ++m) {
    float4 f4 = *reinterpret_cast<const float4*>(&fraw[0][32 * g + 4 * m]);
    uf[4 * m + 0] = __expf(sv[4 * m + 0] + f4.x - Cacc);
    uf[4 * m + 1] = __expf(sv[4 * m + 1] + f4.y - Cacc);
    uf[4 * m + 2] = __expf(sv[4 * m + 2] + f4.z - Cacc);
    uf[4 * m + 3] = __expf(sv[4 * m + 3] + f4.w - Cacc);
  }
  bf16x8 ub[4];
#pragma unroll
  for (int kt = 0; kt < 4; ++kt) {
    bf16x8 t;
#pragma unroll
    for (int e = 0; e < 8; ++e) t[e] = f2bf(uf[8 * kt + e]);
    ub[kt] = t;
  }

  const f32x4 zero4 = {0.f, 0.f, 0.f, 0.f};

  // ---- one scan step consuming exp'd feats row frow of fexp
#define STEP(frow)                                                          \
  {                                                                         \
    float4 ef[8];                                                           \
    _Pragma("unroll") for (int m = 0; m < 8; ++m) ef[m] =                   \
        *reinterpret_cast<const float4*>(&fexp[(frow) * NT + 32 * g + 4 * m]); \
    f32x4 acc[8];                                                           \
    _Pragma("unroll") for (int mt = 0; mt < 8; ++mt) acc[mt] =              \
        __builtin_amdgcn_mfma_f32_16x16x32_bf16(E[mt][0], ub[0], zero4, 0,  \
                                                0, 0);                      \
    _Pragma("unroll") for (int kt = 1; kt < 4; ++kt) {                      \
      _Pragma("unroll") for (int mt = 0; mt < 8; ++mt) acc[mt] =            \
          __builtin_amdgcn_mfma_f32_16x16x32_bf16(E[mt][kt], ub[kt],        \
                                                  acc[mt], 0, 0, 0);        \
    }                                                                       \
    float u0 = __uint_as_float(                                             \
        __builtin_amdgcn_readlane(__float_as_uint(acc[0][0]), 0));          \
    float s = __builtin_amdgcn_rcpf(u0);                                    \
    Cacc += __logf(u0);                                                     \
    _Pragma("unroll") for (int mt = 0; mt < 8; ++mt) {                      \
      uf[4 * mt + 0] = acc[mt][0] * s * ef[mt].x;                           \
      uf[4 * mt + 1] = acc[mt][1] * s * ef[mt].y;                           \
      uf[4 * mt + 2] = acc[mt][2] * s * ef[mt].z;                           \
      uf[4 * mt + 3] = acc[mt][3] * s * ef[mt].w;                           \
    }                                                                       \
    _Pragma("unroll") for (int kt = 0; kt < 4; ++kt) {                      \
      bf16x8 t;                                                             \
      _Pragma("unroll") for (int e = 0; e < 8; ++e)                         \
          t[e] = f2bf(uf[8 * kt + e]);                                      \
      ub[kt] = t;                                                           \
    }                                                                       \
  }

  // chunk 0: rows 1..15 (row 0 consumed by init)
#pragma unroll 4
  for (int trow = 1; trow < CHUNK; ++trow) STEP(trow)

  for (int ch = 1; ch < NCHUNK; ++ch) {
    asm volatile("s_waitcnt vmcnt(0)" ::: "memory");  // chunk ch raw landed
    const int buf = ch & 1;
    EXPPASS(buf)
    if (ch + 1 < NCHUNK) STAGE(ch + 1, buf ^ 1)
#pragma unroll 4
    for (int trow = 0; trow < CHUNK; ++trow) STEP(trow)
  }
#undef STEP
#undef STAGE
#undef EXPPASS

  // ---- final: ans = Cacc + log( sum_j u[j]*exp(stop[j]) )
  float tot = 0.f;
#pragma unroll
  for (int m = 0; m < 8; ++m) {
    float4 s4 = *reinterpret_cast<const float4*>(stop + 32 * g + 4 * m);
    tot += uf[4 * m + 0] * __expf(s4.x) + uf[4 * m + 1] * __expf(s4.y) +
           uf[4 * m + 2] * __expf(s4.z) + uf[4 * m + 3] * __expf(s4.w);
  }
  // lane's tot is its g-group partial (replicated over c). Sum over g bits.
  tot += __shfl_xor(tot, 16);
  tot += __shfl_xor(tot, 32);
  if (tid == 0) fwd_out[b] = Cacc + __logf(tot);
}

__global__ __launch_bounds__(256) void crf_gold_kernel(
    const float* __restrict__ feats, const float* __restrict__ trans,
    const float* __restrict__ start, const float* __restrict__ stop,
    const int* __restrict__ tags, const float* __restrict__ fwd,
    float* __restrict__ diff) {
  const int b = blockIdx.x;
  const int tid = (int)threadIdx.x;
  const int lane = tid & 63;
  const int w = tid >> 6;
  const int* tg = tags + b * T_LEN;
  const float* fb = feats + (size_t)b * T_LEN * NT;

  float acc = 0.f;
  for (int s = tid; s < T_LEN; s += 256) {
    int cu = tg[s];
    acc += fb[s * NT + cu];
    if (s > 0) acc += trans[cu * NT + tg[s - 1]];
  }
#pragma unroll
  for (int off = 1; off <= 32; off <<= 1) acc += __shfl_xor(acc, off);
  __shared__ float wr[4];
  if (lane == 0) wr[w] = acc;
  __syncthreads();
  if (tid == 0) {
    float gold = (wr[0] + wr[1]) + (wr[2] + wr[3]) + start[tg[0]] +
                 stop[tg[T_LEN - 1]];
    diff[b] = fwd[b] - gold;
  }
}

__global__ __launch_bounds__(128) void crf_final_kernel(
    const float* __restrict__ diff, float* __restrict__ out) {
  const int tid = (int)threadIdx.x;
  const int lane = tid & 63;
  const int w = tid >> 6;
  float v = diff[tid];
#pragma unroll
  for (int off = 1; off <= 32; off <<= 1) v += __shfl_xor(v, off);
  __shared__ float wr[2];
  if (lane == 0) wr[w] = v;
  __syncthreads();
  if (tid == 0) out[0] = (wr[0] + wr[1]) * (1.0f / 128.0f);
}

extern "C" void kernel_launch(void* const* d_in, const int* in_sizes, int n_in,
                              void* d_out, int out_size, void* d_ws,
                              size_t ws_size, hipStream_t stream) {
  const float* feats = (const float*)d_in[0];
  const float* trans = (const float*)d_in[1];
  const float* start = (const float*)d_in[2];
  const float* stop = (const float*)d_in[3];
  const int* tags = (const int*)d_in[4];
  // d_in[5] = mask: all-true for this problem; ignored.
  float* ws = (float*)d_ws;
  float* fwd = ws;         // 128 floats
  float* diff = ws + 128;  // 128 floats
  float* out = (float*)d_out;

  crf_forward_kernel<<<128, 64, 0, stream>>>(feats, trans, start, stop, fwd);
  crf_gold_kernel<<<128, 256, 0, stream>>>(feats, trans, start, stop, tags, fwd,
                                           diff);
  crf_final_kernel<<<1, 128, 0, stream>>>(diff, out);
}